// Round 3
// baseline (405.157 us; speedup 1.0000x reference)
//
#include <hip/hip_runtime.h>
#include <hip/hip_bf16.h>

// Problem constants
#define NN    8192   // nodes
#define FIN   256    // input features
#define UNITS 64
#define HEADS 4
#define CTOT  256    // HEADS*UNITS
#define CAP   256    // max edges/row tracked (deg ~ Bin(8192,.004): mean 33, sd 5.7)

__device__ __forceinline__ float bf2f(unsigned short u) {
    union { unsigned int i; float f; } v;
    v.i = ((unsigned int)u) << 16;
    return v.f;
}

// ---------------------------------------------------------------------------
// Kernel 0: dtype probe. A[0][0]==1.0 guaranteed (self-loop).
// fp32: word0 = 0x3F800000 -> low16 == 0x0000 ; bf16: low16 == 0x3F80.
// ---------------------------------------------------------------------------
__global__ void k_detect(const unsigned int* __restrict__ A, int* __restrict__ flag) {
    *flag = ((A[0] & 0xFFFFu) == 0x3F80u) ? 1 : 0;
}

// ---------------------------------------------------------------------------
// Kernel A: feats[n][h*64+u] = sum_f X[n][f] * W[h][f][u]   (fp32 accumulate)
// 64x64 tile per block, 4x4 register micro-tile, LDS-staged fp32.
// grid: (128 row-tiles, 4 heads), block: 256
// ---------------------------------------------------------------------------
__global__ __launch_bounds__(256) void k_proj(const void* __restrict__ Xv,
                                              const void* __restrict__ Wv,
                                              const int* __restrict__ flag,
                                              float* __restrict__ feats) {
    __shared__ float Xt[32 * 68];  // [k][row], stride 68 (16B aligned)
    __shared__ float Wl[32 * 68];  // [k][u]
    const int isbf = *flag;
    const int tid = threadIdx.x;
    const int r0  = blockIdx.x * 64;
    const int h   = blockIdx.y;

    const int r  = (tid & 15) * 4;   // micro-tile row base
    const int cl = (tid >> 4) * 4;   // micro-tile col base

    const int srow = tid >> 2;        // 0..63
    const int skq  = (tid & 3) * 8;   // 0,8,16,24
    const int wk   = tid >> 3;        // 0..31
    const int wu   = (tid & 7) * 8;   // 0..56

    float acc[4][4];
    #pragma unroll
    for (int a = 0; a < 4; ++a)
        #pragma unroll
        for (int b = 0; b < 4; ++b) acc[a][b] = 0.f;

    for (int k0 = 0; k0 < FIN; k0 += 32) {
        __syncthreads();
        if (isbf) {
            const unsigned short* X = (const unsigned short*)Xv;
            const unsigned short* W = (const unsigned short*)Wv;
            const uint4 xv = *reinterpret_cast<const uint4*>(
                X + (size_t)(r0 + srow) * FIN + k0 + skq);
            const unsigned int xs[4] = {xv.x, xv.y, xv.z, xv.w};
            #pragma unroll
            for (int m = 0; m < 4; ++m) {
                Xt[(skq + 2 * m    ) * 68 + srow] = bf2f((unsigned short)(xs[m] & 0xffffu));
                Xt[(skq + 2 * m + 1) * 68 + srow] = bf2f((unsigned short)(xs[m] >> 16));
            }
            const uint4 wv = *reinterpret_cast<const uint4*>(
                W + (size_t)h * (FIN * UNITS) + (size_t)(k0 + wk) * UNITS + wu);
            const unsigned int ws4[4] = {wv.x, wv.y, wv.z, wv.w};
            #pragma unroll
            for (int m = 0; m < 4; ++m) {
                Wl[wk * 68 + wu + 2 * m    ] = bf2f((unsigned short)(ws4[m] & 0xffffu));
                Wl[wk * 68 + wu + 2 * m + 1] = bf2f((unsigned short)(ws4[m] >> 16));
            }
        } else {
            const float* X = (const float*)Xv;
            const float* W = (const float*)Wv;
            const float4* xp = reinterpret_cast<const float4*>(
                X + (size_t)(r0 + srow) * FIN + k0 + skq);
            const float4 x0 = xp[0], x1 = xp[1];
            const float xs[8] = {x0.x, x0.y, x0.z, x0.w, x1.x, x1.y, x1.z, x1.w};
            #pragma unroll
            for (int m = 0; m < 8; ++m) Xt[(skq + m) * 68 + srow] = xs[m];
            const float4* wp = reinterpret_cast<const float4*>(
                W + (size_t)h * (FIN * UNITS) + (size_t)(k0 + wk) * UNITS + wu);
            const float4 w0 = wp[0], w1 = wp[1];
            const float ws8[8] = {w0.x, w0.y, w0.z, w0.w, w1.x, w1.y, w1.z, w1.w};
            #pragma unroll
            for (int m = 0; m < 8; ++m) Wl[wk * 68 + wu + m] = ws8[m];
        }
        __syncthreads();
        #pragma unroll 8
        for (int k = 0; k < 32; ++k) {
            const float4 a4 = *reinterpret_cast<const float4*>(&Xt[k * 68 + r]);
            const float4 b4 = *reinterpret_cast<const float4*>(&Wl[k * 68 + cl]);
            const float av[4] = {a4.x, a4.y, a4.z, a4.w};
            const float bv[4] = {b4.x, b4.y, b4.z, b4.w};
            #pragma unroll
            for (int ri = 0; ri < 4; ++ri)
                #pragma unroll
                for (int ci = 0; ci < 4; ++ci)
                    acc[ri][ci] += av[ri] * bv[ci];
        }
    }
    #pragma unroll
    for (int ri = 0; ri < 4; ++ri) {
        float4 o = make_float4(acc[ri][0], acc[ri][1], acc[ri][2], acc[ri][3]);
        *reinterpret_cast<float4*>(&feats[(size_t)(r0 + r + ri) * CTOT + h * UNITS + cl]) = o;
    }
}

// ---------------------------------------------------------------------------
// Kernel B: a_self[h][n], a_neigh[h][n] dot products. One wave per head,
// 8 rows per block. grid: 1024, block: 256
// ---------------------------------------------------------------------------
__global__ __launch_bounds__(256) void k_attn_vec(const float* __restrict__ feats,
                                                  const void* __restrict__ attsv,
                                                  const void* __restrict__ attnv,
                                                  const int* __restrict__ flag,
                                                  float* __restrict__ s_self,
                                                  float* __restrict__ s_neigh) {
    const int isbf = *flag;
    const int tid  = threadIdx.x;
    const int w    = tid >> 6;   // head
    const int lane = tid & 63;
    float as, an;
    if (isbf) {
        as = bf2f(((const unsigned short*)attsv)[w * UNITS + lane]);
        an = bf2f(((const unsigned short*)attnv)[w * UNITS + lane]);
    } else {
        as = ((const float*)attsv)[w * UNITS + lane];
        an = ((const float*)attnv)[w * UNITS + lane];
    }
    const int n0 = blockIdx.x * 8;
    for (int rr = 0; rr < 8; ++rr) {
        const int n = n0 + rr;
        const float v = feats[(size_t)n * CTOT + tid];
        float ss = v * as;
        float sn = v * an;
        #pragma unroll
        for (int off = 32; off > 0; off >>= 1) {
            ss += __shfl_xor(ss, off, 64);
            sn += __shfl_xor(sn, off, 64);
        }
        if (lane == 0) {
            s_self [w * NN + n] = ss;
            s_neigh[w * NN + n] = sn;
        }
    }
}

// ---------------------------------------------------------------------------
// Kernel C: per row i — scan A row, build edge list, per-head softmax over
// edges, weighted sum of feats rows, ELU, store (dtype follows input flag).
// grid: 8192, block: 256 (wave w == head w)
// ---------------------------------------------------------------------------
__global__ __launch_bounds__(256) void k_gat(const void* __restrict__ Av,
                                             const float* __restrict__ feats,
                                             const float* __restrict__ s_self,
                                             const float* __restrict__ s_neigh,
                                             const int* __restrict__ flag,
                                             void* __restrict__ outv) {
    __shared__ int   ej[CAP];
    __shared__ float sc[HEADS][CAP];
    __shared__ int   cnt;
    const int isbf = *flag;
    const int tid = threadIdx.x;
    const int i   = blockIdx.x;
    if (tid == 0) cnt = 0;
    __syncthreads();

    // ---- phase 1: scan adjacency row, compact nonzero column indices ----
    if (isbf) {
        const unsigned short* Arow = (const unsigned short*)Av + (size_t)i * NN;
        #pragma unroll
        for (int it = 0; it < 4; ++it) {
            const int j0 = it * 2048 + tid * 8;
            const uint4 v = *reinterpret_cast<const uint4*>(Arow + j0);
            const unsigned int vs[4] = {v.x, v.y, v.z, v.w};
            #pragma unroll
            for (int m = 0; m < 4; ++m) {
                if (vs[m] & 0xffffu) {
                    const int p = atomicAdd(&cnt, 1);
                    if (p < CAP) ej[p] = j0 + 2 * m;
                }
                if (vs[m] >> 16) {
                    const int p = atomicAdd(&cnt, 1);
                    if (p < CAP) ej[p] = j0 + 2 * m + 1;
                }
            }
        }
    } else {
        const float* Arow = (const float*)Av + (size_t)i * NN;
        #pragma unroll
        for (int it = 0; it < 4; ++it) {
            const int j0 = it * 2048 + tid * 8;
            const uint4 v0 = *reinterpret_cast<const uint4*>(Arow + j0);
            const uint4 v1 = *reinterpret_cast<const uint4*>(Arow + j0 + 4);
            const unsigned int vs[8] = {v0.x, v0.y, v0.z, v0.w, v1.x, v1.y, v1.z, v1.w};
            #pragma unroll
            for (int m = 0; m < 8; ++m) {
                if (vs[m] != 0u) {
                    const int p = atomicAdd(&cnt, 1);
                    if (p < CAP) ej[p] = j0 + m;
                }
            }
        }
    }
    __syncthreads();
    const int ne = min(cnt, CAP);

    // ---- phase 2a: leaky-relu scores for all heads ----
    float si[HEADS];
    #pragma unroll
    for (int h = 0; h < HEADS; ++h) si[h] = s_self[h * NN + i];
    for (int jj = tid; jj < ne; jj += 256) {
        const int j = ej[jj];
        #pragma unroll
        for (int h = 0; h < HEADS; ++h) {
            const float e = si[h] + s_neigh[h * NN + j];
            sc[h][jj] = (e > 0.f) ? e : 0.2f * e;
        }
    }
    __syncthreads();

    // ---- phase 2b: per-head (per-wave) max + sum-exp ----
    const int w    = tid >> 6;
    const int lane = tid & 63;
    float m = -3.0e38f;
    for (int jj = lane; jj < ne; jj += 64) m = fmaxf(m, sc[w][jj]);
    #pragma unroll
    for (int off = 32; off > 0; off >>= 1) m = fmaxf(m, __shfl_xor(m, off, 64));
    float l = 0.f;
    for (int jj = lane; jj < ne; jj += 64) {
        const float p = __expf(sc[w][jj] - m);
        sc[w][jj] = p;   // wave-private row
        l += p;
    }
    #pragma unroll
    for (int off = 32; off > 0; off >>= 1) l += __shfl_xor(l, off, 64);
    const float rl = (l > 0.f) ? (1.f / l) : 0.f;

    // ---- phase 2c: weighted sum of feats rows; thread = (head w, unit lane) ----
    float o = 0.f;
    for (int jj = 0; jj < ne; ++jj) {
        const int j = ej[jj];            // wave-uniform broadcast
        o += sc[w][jj] * feats[(size_t)j * CTOT + tid];
    }
    o *= rl;
    const float r = (o > 0.f) ? o : (__expf(o) - 1.f);   // ELU, alpha=1

    // ---- output dtype follows input dtype universe ----
    if (isbf) {
        ((__hip_bfloat16*)outv)[(size_t)i * CTOT + tid] = __float2bfloat16(r);
    } else {
        ((float*)outv)[(size_t)i * CTOT + tid] = r;
    }
}

// ---------------------------------------------------------------------------
extern "C" void kernel_launch(void* const* d_in, const int* in_sizes, int n_in,
                              void* d_out, int out_size, void* d_ws, size_t ws_size,
                              hipStream_t stream) {
    const void* X    = d_in[0];
    const void* A    = d_in[1];
    const void* W    = d_in[2];
    const void* atts = d_in[3];
    const void* attn = d_in[4];

    float* feats   = (float*)d_ws;                 // NN*CTOT fp32 = 8 MB
    float* s_self  = feats  + (size_t)NN * CTOT;   // HEADS*NN fp32
    float* s_neigh = s_self + (size_t)HEADS * NN;  // HEADS*NN fp32
    int*   flag    = (int*)(s_neigh + (size_t)HEADS * NN);

    k_detect<<<1, 1, 0, stream>>>((const unsigned int*)A, flag);
    k_proj<<<dim3(NN / 64, HEADS), 256, 0, stream>>>(X, W, flag, feats);
    k_attn_vec<<<NN / 8, 256, 0, stream>>>(feats, atts, attn, flag, s_self, s_neigh);
    k_gat<<<NN, 256, 0, stream>>>(A, feats, s_self, s_neigh, flag, d_out);
}

// Round 4
// 397.132 us; speedup vs baseline: 1.0202x; 1.0202x over previous
//
#include <hip/hip_runtime.h>

// Problem constants (all inputs/outputs proven fp32 in round 3)
#define NN    8192   // nodes
#define FIN   256    // input features
#define UNITS 64
#define HEADS 4
#define CTOT  256    // HEADS*UNITS
#define CAP   256    // max edges/row (deg ~ Bin(8192,.004)+self: mean 34, sd 5.7)

// ---------------------------------------------------------------------------
// Kernel A: feats[n][h*64+u] = sum_f X[n][f] * W[h][f][u]  (fp32, VALU GEMM)
// + fused epilogue: s_self[n*4+h] = feats[n][h,:] . attn_self[h,:]
//                   s_neigh[n*4+h] = feats[n][h,:] . attn_neigh[h,:]
// 64x64 tile per block (one head), 4x4 register micro-tile, LDS-staged.
// grid: (128 row-tiles, 4 heads), block: 256
// ---------------------------------------------------------------------------
__global__ __launch_bounds__(256) void k_proj(const float* __restrict__ X,
                                              const float* __restrict__ W,
                                              const float* __restrict__ atts,
                                              const float* __restrict__ attn,
                                              float* __restrict__ feats,
                                              float* __restrict__ s_self,
                                              float* __restrict__ s_neigh) {
    __shared__ float Xt[32 * 68];   // [k][row], stride 68 (16B aligned)
    __shared__ float Wl[32 * 68];   // [k][u]
    __shared__ float reds[64];      // per-local-row a_self partials
    __shared__ float redn[64];
    const int tid = threadIdx.x;
    const int r0  = blockIdx.x * 64;
    const int h   = blockIdx.y;

    const int r  = (tid & 15) * 4;   // micro-tile row base
    const int cl = (tid >> 4) * 4;   // micro-tile col base

    const int srow = tid >> 2;        // 0..63
    const int skq  = (tid & 3) * 8;   // 0,8,16,24
    const int wk   = tid >> 3;        // 0..31
    const int wu   = (tid & 7) * 8;   // 0..56

    if (tid < 64) { reds[tid] = 0.f; redn[tid] = 0.f; }  // visible after 1st barrier

    float acc[4][4];
    #pragma unroll
    for (int a = 0; a < 4; ++a)
        #pragma unroll
        for (int b = 0; b < 4; ++b) acc[a][b] = 0.f;

    for (int k0 = 0; k0 < FIN; k0 += 32) {
        __syncthreads();
        {   // stage X tile transposed: Xt[k][row]
            const float4* xp = reinterpret_cast<const float4*>(
                X + (size_t)(r0 + srow) * FIN + k0 + skq);
            const float4 x0 = xp[0], x1 = xp[1];
            const float xs[8] = {x0.x, x0.y, x0.z, x0.w, x1.x, x1.y, x1.z, x1.w};
            #pragma unroll
            for (int m = 0; m < 8; ++m) Xt[(skq + m) * 68 + srow] = xs[m];
        }
        {   // stage W tile: Wl[k][u]
            const float4* wp = reinterpret_cast<const float4*>(
                W + (size_t)h * (FIN * UNITS) + (size_t)(k0 + wk) * UNITS + wu);
            const float4 w0 = wp[0], w1 = wp[1];
            const float ws8[8] = {w0.x, w0.y, w0.z, w0.w, w1.x, w1.y, w1.z, w1.w};
            #pragma unroll
            for (int m = 0; m < 8; ++m) Wl[wk * 68 + wu + m] = ws8[m];
        }
        __syncthreads();
        #pragma unroll 8
        for (int k = 0; k < 32; ++k) {
            const float4 a4 = *reinterpret_cast<const float4*>(&Xt[k * 68 + r]);
            const float4 b4 = *reinterpret_cast<const float4*>(&Wl[k * 68 + cl]);
            const float av[4] = {a4.x, a4.y, a4.z, a4.w};
            const float bv[4] = {b4.x, b4.y, b4.z, b4.w};
            #pragma unroll
            for (int ri = 0; ri < 4; ++ri)
                #pragma unroll
                for (int ci = 0; ci < 4; ++ci)
                    acc[ri][ci] += av[ri] * bv[ci];
        }
    }

    // feats store + attention-vector partial dots
    float as4[4], an4[4];
    #pragma unroll
    for (int ci = 0; ci < 4; ++ci) {
        as4[ci] = atts[h * UNITS + cl + ci];
        an4[ci] = attn[h * UNITS + cl + ci];
    }
    #pragma unroll
    for (int ri = 0; ri < 4; ++ri) {
        float4 o = make_float4(acc[ri][0], acc[ri][1], acc[ri][2], acc[ri][3]);
        *reinterpret_cast<float4*>(&feats[(size_t)(r0 + r + ri) * CTOT + h * UNITS + cl]) = o;
        const float ps = acc[ri][0] * as4[0] + acc[ri][1] * as4[1]
                       + acc[ri][2] * as4[2] + acc[ri][3] * as4[3];
        const float pn = acc[ri][0] * an4[0] + acc[ri][1] * an4[1]
                       + acc[ri][2] * an4[2] + acc[ri][3] * an4[3];
        atomicAdd(&reds[r + ri], ps);   // ds_add_f32, 16-way per row
        atomicAdd(&redn[r + ri], pn);
    }
    __syncthreads();
    if (tid < 64) {
        s_self [((size_t)(r0 + tid) << 2) + h] = reds[tid];  // [n][4] interleaved
        s_neigh[((size_t)(r0 + tid) << 2) + h] = redn[tid];
    }
}

// ---------------------------------------------------------------------------
// Kernel B: per row i — scan A row (coalesced), compact edges, per-head
// (=per-wave) softmax over edges, x4-unrolled weighted gather of feats rows,
// ELU, fp32 store. grid: 8192, block: 256
// ---------------------------------------------------------------------------
__global__ __launch_bounds__(256) void k_gat(const float* __restrict__ A,
                                             const float* __restrict__ feats,
                                             const float* __restrict__ s_self,
                                             const float* __restrict__ s_neigh,
                                             float* __restrict__ out) {
    __shared__ int   ej[CAP];
    __shared__ float sc[HEADS][CAP];
    __shared__ int   cnt;
    const int tid = threadIdx.x;
    const int i   = blockIdx.x;
    if (tid == 0) cnt = 0;
    __syncthreads();

    // ---- phase 1: scan row, build edge list (popc + 1 atomic per thread) ----
    {
        const float4* Arow4 = reinterpret_cast<const float4*>(A + (size_t)i * NN);
        unsigned mask = 0;
        #pragma unroll
        for (int q = 0; q < 8; ++q) {           // lane-contiguous: 1 KB/wave/instr
            const float4 v = Arow4[q * 256 + tid];
            mask |= (v.x != 0.f ? 1u : 0u) << (4 * q);
            mask |= (v.y != 0.f ? 1u : 0u) << (4 * q + 1);
            mask |= (v.z != 0.f ? 1u : 0u) << (4 * q + 2);
            mask |= (v.w != 0.f ? 1u : 0u) << (4 * q + 3);
        }
        const int c = __popc(mask);
        int base = 0;
        if (c) base = atomicAdd(&cnt, c);
        while (mask) {
            const int b = __ffs(mask) - 1;
            mask &= mask - 1;
            if (base < CAP) ej[base] = (b >> 2) * 1024 + tid * 4 + (b & 3);
            ++base;
        }
    }
    __syncthreads();
    const int ne = min(cnt, CAP);

    // ---- phase 2: wave w handles head w (scores wave-private in sc[w]) ----
    const int w    = tid >> 6;
    const int lane = tid & 63;
    const float si = s_self[((size_t)i << 2) + w];
    float m = -3.0e38f;
    for (int jj = lane; jj < ne; jj += 64) {
        const int j = ej[jj];
        float e = si + s_neigh[((size_t)j << 2) + w];
        e = (e > 0.f) ? e : 0.2f * e;            // leaky-relu(0.2)
        sc[w][jj] = e;
        m = fmaxf(m, e);
    }
    #pragma unroll
    for (int off = 32; off > 0; off >>= 1) m = fmaxf(m, __shfl_xor(m, off, 64));
    float l = 0.f;
    for (int jj = lane; jj < ne; jj += 64) {
        const float p = __expf(sc[w][jj] - m);
        sc[w][jj] = p;
        l += p;
    }
    #pragma unroll
    for (int off = 32; off > 0; off >>= 1) l += __shfl_xor(l, off, 64);
    const float rl = 1.f / l;                    // ne>=1 (self-loop) -> l>=1

    // ---- phase 3: weighted feats gather, x4 unrolled for latency hiding ----
    const float* fb = feats + tid;               // thread = (head w, unit lane)
    float o0 = 0.f, o1 = 0.f, o2 = 0.f, o3 = 0.f;
    int jj = 0;
    for (; jj + 4 <= ne; jj += 4) {
        const int ja = ej[jj], jb = ej[jj + 1], jc = ej[jj + 2], jd = ej[jj + 3];
        const float pa = sc[w][jj],     pb = sc[w][jj + 1];
        const float pc = sc[w][jj + 2], pd = sc[w][jj + 3];
        o0 += pa * fb[(size_t)ja * CTOT];
        o1 += pb * fb[(size_t)jb * CTOT];
        o2 += pc * fb[(size_t)jc * CTOT];
        o3 += pd * fb[(size_t)jd * CTOT];
    }
    for (; jj < ne; ++jj) o0 += sc[w][jj] * fb[(size_t)ej[jj] * CTOT];
    const float o = ((o0 + o1) + (o2 + o3)) * rl;
    const float rr = (o > 0.f) ? o : (__expf(o) - 1.f);   // ELU, alpha=1
    out[(size_t)i * CTOT + tid] = rr;
}

// ---------------------------------------------------------------------------
extern "C" void kernel_launch(void* const* d_in, const int* in_sizes, int n_in,
                              void* d_out, int out_size, void* d_ws, size_t ws_size,
                              hipStream_t stream) {
    const float* X    = (const float*)d_in[0];
    const float* A    = (const float*)d_in[1];
    const float* W    = (const float*)d_in[2];
    const float* atts = (const float*)d_in[3];
    const float* attn = (const float*)d_in[4];

    float* feats   = (float*)d_ws;                      // NN*CTOT fp32 = 8 MB
    float* s_self  = feats  + (size_t)NN * CTOT;        // NN*4 fp32 (interleaved [n][h])
    float* s_neigh = s_self + (size_t)NN * HEADS;       // NN*4 fp32

    k_proj<<<dim3(NN / 64, HEADS), 256, 0, stream>>>(X, W, atts, attn,
                                                     feats, s_self, s_neigh);
    k_gat<<<NN, 256, 0, stream>>>(A, feats, s_self, s_neigh, (float*)d_out);
}

// Round 5
// 393.305 us; speedup vs baseline: 1.0301x; 1.0097x over previous
//
#include <hip/hip_runtime.h>

// Problem constants (all inputs/outputs fp32, proven in round 3)
#define NN    8192   // nodes
#define FIN   256    // input features
#define UNITS 64
#define HEADS 4
#define CTOT  256    // HEADS*UNITS
#define CAP   256    // max edges/row (deg ~ Bin(8192,.004)+self: mean 34, sd 5.7)
#define PBLK  512    // projection blocks (128 row-tiles x 4 heads)

// ---------------------------------------------------------------------------
// Kernel 1 — heterogeneous grid:
//   blocks [0, PBLK):     64x64-tile VALU GEMM feats = X·W[h] + fused
//                         attention-vector dots -> s_self/s_neigh [n][4]
//   blocks [PBLK, +NN):   scan A row (i = bid-PBLK), compact edge list to ws
// The GEMM is compute-bound and the scan is HBM-bound; co-residency across
// CUs overlaps them (same-stream kernels cannot).
// ---------------------------------------------------------------------------
__global__ __launch_bounds__(256) void k_proj_scan(const float* __restrict__ X,
                                                   const float* __restrict__ W,
                                                   const float* __restrict__ atts,
                                                   const float* __restrict__ attn,
                                                   const float* __restrict__ A,
                                                   float* __restrict__ feats,
                                                   float* __restrict__ s_self,
                                                   float* __restrict__ s_neigh,
                                                   int*   __restrict__ ej_g,
                                                   int*   __restrict__ cnt_g) {
    const int tid = threadIdx.x;
    const int bid = blockIdx.x;

    if (bid >= PBLK) {
        // ================= A-row scan / edge compaction =================
        __shared__ int ej[CAP];
        __shared__ int cnt;
        const int i = bid - PBLK;
        if (tid == 0) cnt = 0;
        __syncthreads();
        {
            const float4* Arow4 = reinterpret_cast<const float4*>(A + (size_t)i * NN);
            unsigned mask = 0;
            #pragma unroll
            for (int q = 0; q < 8; ++q) {        // 1 KB/wave/instr, coalesced
                const float4 v = Arow4[q * 256 + tid];
                mask |= (v.x != 0.f ? 1u : 0u) << (4 * q);
                mask |= (v.y != 0.f ? 1u : 0u) << (4 * q + 1);
                mask |= (v.z != 0.f ? 1u : 0u) << (4 * q + 2);
                mask |= (v.w != 0.f ? 1u : 0u) << (4 * q + 3);
            }
            const int c = __popc(mask);
            int base = 0;
            if (c) base = atomicAdd(&cnt, c);
            while (mask) {
                const int b = __ffs(mask) - 1;
                mask &= mask - 1;
                if (base < CAP) ej[base] = (b >> 2) * 1024 + tid * 4 + (b & 3);
                ++base;
            }
        }
        __syncthreads();
        const int ne = min(cnt, CAP);
        if (tid < ne) ej_g[(size_t)i * CAP + tid] = ej[tid];
        if (tid == 0) cnt_g[i] = ne;
        return;
    }

    // ===================== projection GEMM (one head-tile) =====================
    __shared__ float Xt[32 * 68];   // [k][row], stride 68
    __shared__ float Wl[32 * 68];   // [k][u]
    __shared__ float reds[64];
    __shared__ float redn[64];
    const int rt = bid & 127;        // row tile
    const int h  = bid >> 7;         // head
    const int r0 = rt * 64;

    const int r  = (tid & 15) * 4;   // micro-tile row base
    const int cl = (tid >> 4) * 4;   // micro-tile col base
    const int srow = tid >> 2;       // 0..63
    const int skq  = (tid & 3) * 8;  // 0,8,16,24
    const int wk   = tid >> 3;       // 0..31
    const int wu   = (tid & 7) * 8;  // 0..56

    if (tid < 64) { reds[tid] = 0.f; redn[tid] = 0.f; }

    float acc[4][4];
    #pragma unroll
    for (int a = 0; a < 4; ++a)
        #pragma unroll
        for (int b = 0; b < 4; ++b) acc[a][b] = 0.f;

    for (int k0 = 0; k0 < FIN; k0 += 32) {
        __syncthreads();
        {
            const float4* xp = reinterpret_cast<const float4*>(
                X + (size_t)(r0 + srow) * FIN + k0 + skq);
            const float4 x0 = xp[0], x1 = xp[1];
            const float xs[8] = {x0.x, x0.y, x0.z, x0.w, x1.x, x1.y, x1.z, x1.w};
            #pragma unroll
            for (int m = 0; m < 8; ++m) Xt[(skq + m) * 68 + srow] = xs[m];
        }
        {
            const float4* wp = reinterpret_cast<const float4*>(
                W + (size_t)h * (FIN * UNITS) + (size_t)(k0 + wk) * UNITS + wu);
            const float4 w0 = wp[0], w1 = wp[1];
            const float ws8[8] = {w0.x, w0.y, w0.z, w0.w, w1.x, w1.y, w1.z, w1.w};
            #pragma unroll
            for (int m = 0; m < 8; ++m) Wl[wk * 68 + wu + m] = ws8[m];
        }
        __syncthreads();
        #pragma unroll 8
        for (int k = 0; k < 32; ++k) {
            const float4 a4 = *reinterpret_cast<const float4*>(&Xt[k * 68 + r]);
            const float4 b4 = *reinterpret_cast<const float4*>(&Wl[k * 68 + cl]);
            const float av[4] = {a4.x, a4.y, a4.z, a4.w};
            const float bv[4] = {b4.x, b4.y, b4.z, b4.w};
            #pragma unroll
            for (int ri = 0; ri < 4; ++ri)
                #pragma unroll
                for (int ci = 0; ci < 4; ++ci)
                    acc[ri][ci] += av[ri] * bv[ci];
        }
    }

    float as4[4], an4[4];
    #pragma unroll
    for (int ci = 0; ci < 4; ++ci) {
        as4[ci] = atts[h * UNITS + cl + ci];
        an4[ci] = attn[h * UNITS + cl + ci];
    }
    #pragma unroll
    for (int ri = 0; ri < 4; ++ri) {
        float4 o = make_float4(acc[ri][0], acc[ri][1], acc[ri][2], acc[ri][3]);
        *reinterpret_cast<float4*>(&feats[(size_t)(r0 + r + ri) * CTOT + h * UNITS + cl]) = o;
        const float ps = acc[ri][0] * as4[0] + acc[ri][1] * as4[1]
                       + acc[ri][2] * as4[2] + acc[ri][3] * as4[3];
        const float pn = acc[ri][0] * an4[0] + acc[ri][1] * an4[1]
                       + acc[ri][2] * an4[2] + acc[ri][3] * an4[3];
        atomicAdd(&reds[r + ri], ps);   // LDS ds_add, 16-way per row
        atomicAdd(&redn[r + ri], pn);
    }
    __syncthreads();
    if (tid < 64) {
        s_self [((size_t)(r0 + tid) << 2) + h] = reds[tid];  // [n][4]
        s_neigh[((size_t)(r0 + tid) << 2) + h] = redn[tid];
    }
}

// ---------------------------------------------------------------------------
// Kernel 2: per row i — load edge list, per-head (=per-wave) softmax,
// x4-unrolled weighted gather of feats rows (LLC-resident), ELU, store.
// grid: 8192, block: 256
// ---------------------------------------------------------------------------
__global__ __launch_bounds__(256) void k_gat(const int*   __restrict__ ej_g,
                                             const int*   __restrict__ cnt_g,
                                             const float* __restrict__ feats,
                                             const float* __restrict__ s_self,
                                             const float* __restrict__ s_neigh,
                                             float* __restrict__ out) {
    __shared__ int   ej[CAP];
    __shared__ float sc[HEADS][CAP];
    const int tid = threadIdx.x;
    const int i   = blockIdx.x;
    const int ne  = cnt_g[i];
    if (tid < ne) ej[tid] = ej_g[(size_t)i * CAP + tid];
    __syncthreads();

    // ---- per-head softmax over edges (wave w == head w) ----
    const int w    = tid >> 6;
    const int lane = tid & 63;
    const float si = s_self[((size_t)i << 2) + w];
    float m = -3.0e38f;
    for (int jj = lane; jj < ne; jj += 64) {
        const int j = ej[jj];
        float e = si + s_neigh[((size_t)j << 2) + w];
        e = (e > 0.f) ? e : 0.2f * e;            // leaky-relu(0.2)
        sc[w][jj] = e;
        m = fmaxf(m, e);
    }
    #pragma unroll
    for (int off = 32; off > 0; off >>= 1) m = fmaxf(m, __shfl_xor(m, off, 64));
    float l = 0.f;
    for (int jj = lane; jj < ne; jj += 64) {
        const float p = __expf(sc[w][jj] - m);
        sc[w][jj] = p;
        l += p;
    }
    #pragma unroll
    for (int off = 32; off > 0; off >>= 1) l += __shfl_xor(l, off, 64);
    const float rl = 1.f / l;                    // ne>=1 (self-loop)

    // ---- weighted feats gather, x4 unrolled ----
    const float* fb = feats + tid;               // thread = (head w, unit lane)
    float o0 = 0.f, o1 = 0.f, o2 = 0.f, o3 = 0.f;
    int jj = 0;
    for (; jj + 4 <= ne; jj += 4) {
        const int ja = ej[jj], jb = ej[jj + 1], jc = ej[jj + 2], jd = ej[jj + 3];
        const float pa = sc[w][jj],     pb = sc[w][jj + 1];
        const float pc = sc[w][jj + 2], pd = sc[w][jj + 3];
        o0 += pa * fb[(size_t)ja * CTOT];
        o1 += pb * fb[(size_t)jb * CTOT];
        o2 += pc * fb[(size_t)jc * CTOT];
        o3 += pd * fb[(size_t)jd * CTOT];
    }
    for (; jj < ne; ++jj) o0 += sc[w][jj] * fb[(size_t)ej[jj] * CTOT];
    const float o = ((o0 + o1) + (o2 + o3)) * rl;
    const float rr = (o > 0.f) ? o : (__expf(o) - 1.f);   // ELU, alpha=1
    out[(size_t)i * CTOT + tid] = rr;
}

// ---------------------------------------------------------------------------
extern "C" void kernel_launch(void* const* d_in, const int* in_sizes, int n_in,
                              void* d_out, int out_size, void* d_ws, size_t ws_size,
                              hipStream_t stream) {
    const float* X    = (const float*)d_in[0];
    const float* A    = (const float*)d_in[1];
    const float* W    = (const float*)d_in[2];
    const float* atts = (const float*)d_in[3];
    const float* attn = (const float*)d_in[4];

    float* feats   = (float*)d_ws;                      // NN*CTOT fp32 = 8 MB
    float* s_self  = feats  + (size_t)NN * CTOT;        // NN*4 fp32
    float* s_neigh = s_self + (size_t)NN * HEADS;       // NN*4 fp32
    int*   cnt_g   = (int*)(s_neigh + (size_t)NN * HEADS);   // NN ints
    int*   ej_g    = cnt_g + NN;                        // NN*CAP ints = 8 MB

    k_proj_scan<<<PBLK + NN, 256, 0, stream>>>(X, W, atts, attn, A,
                                               feats, s_self, s_neigh, ej_g, cnt_g);
    k_gat<<<NN, 256, 0, stream>>>(ej_g, cnt_g, feats, s_self, s_neigh, (float*)d_out);
}